// Round 1
// baseline (240.865 us; speedup 1.0000x reference)
//
#include <hip/hip_runtime.h>

// GMM-GCN layer, MI355X (gfx950).
// N=4096 nodes, F=O=128, K=4 mixture components.
//
// Pipeline:
//  K0:  prep fp16 weight tiles (W, W^2) in MFMA-ready [fc][g][o][8] layout,
//       muh/varh fp16 tables, invvar fp32 table.
//  K1a: gamma[k][n] = softmax_k(pi[k] - 0.5 * sum_f masked (x-mu)^2/var)
//       (softmax-constant terms of log_n cancel -> dropped exactly)
//  K1b: MFMA fp16 GEMM: tx = mean_mat @ W, tcov = var_mat @ W^2,
//       written transposed as Bws[col'][m] fp16, col' = k*128+o (x), 512+k*128+o (cov)
//  K2:  big fused dual GEMM: conv_x = shift @ tx, conv_cov = shift^2 @ tcov
//       (shift fp32 -> fp16 * 2^12 in-register; squared in-register -> *2^24)
//       K-split = 4 -> partials in convbuf[ks][n][1024]
//  K3:  ex_relu + gamma-weighted sum over k -> out[n][o]

#define NN 4096
#define FF 128
#define KK 4

typedef _Float16 f16;
typedef f16 f16x8 __attribute__((ext_vector_type(8)));
typedef f16 f16x4 __attribute__((ext_vector_type(4)));
typedef float f32x4 __attribute__((ext_vector_type(4)));

typedef const __attribute__((address_space(1))) void* gptr1_t;
typedef __attribute__((address_space(3))) void* lptr3_t;

__device__ __forceinline__ void gload_lds16(const void* g, void* l) {
  // async global->LDS, 16 bytes/lane; LDS dest = wave-uniform base + lane*16
  __builtin_amdgcn_global_load_lds((gptr1_t)g, (lptr3_t)l, 16, 0, 0);
}

__device__ __forceinline__ bool is_nan_bits(float x) {
  return (__float_as_uint(x) & 0x7fffffffu) > 0x7f800000u;  // fast-math-proof
}

// ---------------------------------------------------------------- K0: prep
__global__ __launch_bounds__(256) void k0_prep(
    const float* __restrict__ W, const float* __restrict__ mu,
    const float* __restrict__ sigma, f16* __restrict__ Wx, f16* __restrict__ Wc,
    f16* __restrict__ muh, f16* __restrict__ varh, float* __restrict__ invvar) {
  int tid = blockIdx.x * 256 + threadIdx.x;
  for (int i = tid; i < 16384; i += (int)gridDim.x * 256) {
    // layout [fc 4][g 4][o 128][j 8];  f = fc*32 + g*8 + j
    int j = i & 7;
    int o = (i >> 3) & 127;
    int g = (i >> 10) & 3;
    int fc = i >> 12;
    int f = fc * 32 + g * 8 + j;
    float w = W[f * 128 + o];
    Wx[i] = (f16)w;
    Wc[i] = (f16)(w * w);
  }
  if (tid < 512) {
    muh[tid] = (f16)mu[tid];
    float s = sigma[tid];
    varh[tid] = (f16)expf(s);
    invvar[tid] = expf(-s);
  }
}

// ---------------------------------------------------------------- K1a: gamma
__global__ __launch_bounds__(256) void k1a_gamma(
    const float* __restrict__ feats, const float* __restrict__ mu,
    const float* __restrict__ pi, const float* __restrict__ invvar,
    float* __restrict__ gamma) {
  int wid = threadIdx.x >> 6, lane = threadIdx.x & 63;
  int n = blockIdx.x * 4 + wid;
  const float* rp = feats + (long)n * FF;
  float x0 = rp[lane], x1 = rp[lane + 64];
  bool nan0 = is_nan_bits(x0), nan1 = is_nan_bits(x1);
  float acc[KK];
#pragma unroll
  for (int k = 0; k < KK; ++k) {
    float d0 = x0 - mu[k * FF + lane];
    float d1 = x1 - mu[k * FF + lane + 64];
    float t0 = nan0 ? 0.f : d0 * d0 * invvar[k * FF + lane];
    float t1 = nan1 ? 0.f : d1 * d1 * invvar[k * FF + lane + 64];
    acc[k] = t0 + t1;
  }
#pragma unroll
  for (int off = 32; off > 0; off >>= 1) {
#pragma unroll
    for (int k = 0; k < KK; ++k) acc[k] += __shfl_down(acc[k], off);
  }
  if (lane == 0) {
    float lg[KK], m = -1e30f;
#pragma unroll
    for (int k = 0; k < KK; ++k) {
      lg[k] = pi[k] - 0.5f * acc[k];
      m = fmaxf(m, lg[k]);
    }
    float e[KK], s = 0.f;
#pragma unroll
    for (int k = 0; k < KK; ++k) {
      e[k] = expf(lg[k] - m);
      s += e[k];
    }
    float inv = 1.f / s;
#pragma unroll
    for (int k = 0; k < KK; ++k) gamma[k * NN + n] = e[k] * inv;
  }
}

// ------------------------------------------------- K1b: imputation GEMMs
// grid = 4 (k) * 32 (row blocks); 256 threads; 128x128 tile, Kred = F = 128.
__global__ __launch_bounds__(256, 2) void k1b_transform(
    const float* __restrict__ feats, const f16* __restrict__ Wx,
    const f16* __restrict__ Wc, const f16* __restrict__ muh,
    const f16* __restrict__ varh, f16* __restrict__ Bws) {
  __shared__ __align__(16) f16 lds[2][4][4][128][8];  // [buf][part][g][idx][8] = 64 KB
  int bid = blockIdx.x;
  int row = bid & 31;
  int kc = bid >> 5;  // component
  int n0 = row * 128;
  int tid = threadIdx.x;
  int wid = tid >> 6, lane = tid & 63;
  int wr = wid >> 1, wc = wid & 1;
  int fr = lane & 15, fg = lane >> 4;
  int sn = tid >> 1, sh = tid & 1;

  f32x4 accx[4][4], accc[4][4];
#pragma unroll
  for (int a = 0; a < 4; ++a)
#pragma unroll
    for (int b = 0; b < 4; ++b) {
      accx[a][b] = f32x4{0.f, 0.f, 0.f, 0.f};
      accc[a][b] = f32x4{0.f, 0.f, 0.f, 0.f};
    }

  const int NT = 4;  // 128 / 32
  float xs[16];
  f16 mh[16], vh[16];

  auto loadA = [&](int t) {
    const float* ap = feats + (long)(n0 + sn) * FF + t * 32 + sh * 16;
    *(f32x4*)(xs + 0) = *(const f32x4*)(ap + 0);
    *(f32x4*)(xs + 4) = *(const f32x4*)(ap + 4);
    *(f32x4*)(xs + 8) = *(const f32x4*)(ap + 8);
    *(f32x4*)(xs + 12) = *(const f32x4*)(ap + 12);
    const f16* mp = muh + kc * FF + t * 32 + sh * 16;
    const f16* vp = varh + kc * FF + t * 32 + sh * 16;
    *(f16x8*)(mh + 0) = *(const f16x8*)(mp + 0);
    *(f16x8*)(mh + 8) = *(const f16x8*)(mp + 8);
    *(f16x8*)(vh + 0) = *(const f16x8*)(vp + 0);
    *(f16x8*)(vh + 8) = *(const f16x8*)(vp + 8);
  };
  auto writeA = [&](int buf) {
    f16 am[16], av[16];
#pragma unroll
    for (int j = 0; j < 16; ++j) {
      float x = xs[j];
      bool nn = is_nan_bits(x);
      am[j] = nn ? mh[j] : (f16)x;
      av[j] = nn ? vh[j] : (f16)0.f;
    }
    *(f16x8*)&lds[buf][0][2 * sh + 0][sn][0] = *(f16x8*)(am + 0);
    *(f16x8*)&lds[buf][0][2 * sh + 1][sn][0] = *(f16x8*)(am + 8);
    *(f16x8*)&lds[buf][1][2 * sh + 0][sn][0] = *(f16x8*)(av + 0);
    *(f16x8*)&lds[buf][1][2 * sh + 1][sn][0] = *(f16x8*)(av + 8);
  };
  auto stageB = [&](int t, int buf) {
#pragma unroll
    for (int r = 0; r < 2; ++r) {
      int c = r * 256 + tid;      // chunk id (per-lane global addr)
      int cb = r * 256 + wid * 64;  // wave-uniform LDS chunk base
      gload_lds16(Wx + (long)t * 4096 + (long)c * 8, (f16*)&lds[buf][2][0][0][0] + (long)cb * 8);
      gload_lds16(Wc + (long)t * 4096 + (long)c * 8, (f16*)&lds[buf][3][0][0][0] + (long)cb * 8);
    }
  };
  auto compute = [&](int buf) {
    f16x8 am[4], av[4], bx[4], bc[4];
#pragma unroll
    for (int mf = 0; mf < 4; ++mf) {
      am[mf] = *(f16x8*)&lds[buf][0][fg][wr * 64 + mf * 16 + fr][0];
      av[mf] = *(f16x8*)&lds[buf][1][fg][wr * 64 + mf * 16 + fr][0];
    }
#pragma unroll
    for (int nf = 0; nf < 4; ++nf) {
      bx[nf] = *(f16x8*)&lds[buf][2][fg][wc * 64 + nf * 16 + fr][0];
      bc[nf] = *(f16x8*)&lds[buf][3][fg][wc * 64 + nf * 16 + fr][0];
    }
#pragma unroll
    for (int mf = 0; mf < 4; ++mf)
#pragma unroll
      for (int nf = 0; nf < 4; ++nf) {
        accx[mf][nf] = __builtin_amdgcn_mfma_f32_16x16x32_f16(am[mf], bx[nf], accx[mf][nf], 0, 0, 0);
        accc[mf][nf] = __builtin_amdgcn_mfma_f32_16x16x32_f16(av[mf], bc[nf], accc[mf][nf], 0, 0, 0);
      }
  };

  stageB(0, 0);
  loadA(0);
  writeA(0);
  __syncthreads();
  for (int t = 0; t < NT; ++t) {
    int cur = t & 1, nxt = cur ^ 1;
    if (t + 1 < NT) {
      stageB(t + 1, nxt);
      loadA(t + 1);
    }
    compute(cur);
    if (t + 1 < NT) writeA(nxt);
    __syncthreads();
  }

  // epilogue: write Bws[col'][n] fp16, packing 4 consecutive n (8 B stores)
#pragma unroll
  for (int mf = 0; mf < 4; ++mf) {
    int nbase = n0 + wr * 64 + mf * 16 + fg * 4;
#pragma unroll
    for (int nf = 0; nf < 4; ++nf) {
      int col = wc * 64 + nf * 16 + fr;
      f16x4 px, pc;
#pragma unroll
      for (int j = 0; j < 4; ++j) {
        px[j] = (f16)accx[mf][nf][j];
        pc[j] = (f16)accc[mf][nf][j];
      }
      *(f16x4*)(Bws + (long)(kc * 128 + col) * NN + nbase) = px;
      *(f16x4*)(Bws + (long)(512 + kc * 128 + col) * NN + nbase) = pc;
    }
  }
}

// ------------------------------------------------- K2: big fused dual GEMM
// grid = nks * 4 (k) * 32 (row); bid = ks*128 + k*32 + row  (XCD-friendly:
// the 4 k-blocks sharing one A row-panel have equal bid%8 -> same XCD L2).
__global__ __launch_bounds__(256, 2) void k2_conv(
    const float* __restrict__ shift, const f16* __restrict__ Bws,
    float* __restrict__ convbuf, int mlen) {
  __shared__ __align__(16) f16 lds[2][4][4][128][8];  // [buf][part: s,s2,Bx,Bc][g][idx][8]
  int bid = blockIdx.x;
  int row = bid & 31;
  int kc = (bid >> 5) & 3;
  int ks = bid >> 7;
  int n0 = row * 128;
  int m0 = ks * mlen;
  int nt = mlen / 32;
  int tid = threadIdx.x;
  int wid = tid >> 6, lane = tid & 63;
  int wr = wid >> 1, wc = wid & 1;
  int fr = lane & 15, fg = lane >> 4;
  int sn = tid >> 1, sh = tid & 1;

  f32x4 accx[4][4], accc[4][4];
#pragma unroll
  for (int a = 0; a < 4; ++a)
#pragma unroll
    for (int b = 0; b < 4; ++b) {
      accx[a][b] = f32x4{0.f, 0.f, 0.f, 0.f};
      accc[a][b] = f32x4{0.f, 0.f, 0.f, 0.f};
    }

  float xs[16];
  auto loadA = [&](int t) {
    const float* ap = shift + (long)(n0 + sn) * NN + m0 + t * 32 + sh * 16;
    *(f32x4*)(xs + 0) = *(const f32x4*)(ap + 0);
    *(f32x4*)(xs + 4) = *(const f32x4*)(ap + 4);
    *(f32x4*)(xs + 8) = *(const f32x4*)(ap + 8);
    *(f32x4*)(xs + 12) = *(const f32x4*)(ap + 12);
  };
  auto writeA = [&](int buf) {
    f16 sm[16], s2[16];
#pragma unroll
    for (int j = 0; j < 16; ++j) {
      f16 s = (f16)(xs[j] * 4096.f);  // scale into fp16-normal range
      sm[j] = s;
      s2[j] = s * s;  // = shift^2 * 2^24
    }
    *(f16x8*)&lds[buf][0][2 * sh + 0][sn][0] = *(f16x8*)(sm + 0);
    *(f16x8*)&lds[buf][0][2 * sh + 1][sn][0] = *(f16x8*)(sm + 8);
    *(f16x8*)&lds[buf][1][2 * sh + 0][sn][0] = *(f16x8*)(s2 + 0);
    *(f16x8*)&lds[buf][1][2 * sh + 1][sn][0] = *(f16x8*)(s2 + 8);
  };
  auto stageB = [&](int t, int buf) {
#pragma unroll
    for (int r = 0; r < 2; ++r) {
      int c = r * 256 + tid;
      int g = c >> 7, col = c & 127;
      int cb = r * 256 + wid * 64;
      const f16* gx = Bws + (long)(kc * 128 + col) * NN + m0 + t * 32 + g * 8;
      const f16* gc = Bws + (long)(512 + kc * 128 + col) * NN + m0 + t * 32 + g * 8;
      gload_lds16(gx, (f16*)&lds[buf][2][0][0][0] + (long)cb * 8);
      gload_lds16(gc, (f16*)&lds[buf][3][0][0][0] + (long)cb * 8);
    }
  };
  auto compute = [&](int buf) {
    f16x8 am[4], av[4], bx[4], bc[4];
#pragma unroll
    for (int mf = 0; mf < 4; ++mf) {
      am[mf] = *(f16x8*)&lds[buf][0][fg][wr * 64 + mf * 16 + fr][0];
      av[mf] = *(f16x8*)&lds[buf][1][fg][wr * 64 + mf * 16 + fr][0];
    }
#pragma unroll
    for (int nf = 0; nf < 4; ++nf) {
      bx[nf] = *(f16x8*)&lds[buf][2][fg][wc * 64 + nf * 16 + fr][0];
      bc[nf] = *(f16x8*)&lds[buf][3][fg][wc * 64 + nf * 16 + fr][0];
    }
#pragma unroll
    for (int mf = 0; mf < 4; ++mf)
#pragma unroll
      for (int nf = 0; nf < 4; ++nf) {
        accx[mf][nf] = __builtin_amdgcn_mfma_f32_16x16x32_f16(am[mf], bx[nf], accx[mf][nf], 0, 0, 0);
        accc[mf][nf] = __builtin_amdgcn_mfma_f32_16x16x32_f16(av[mf], bc[nf], accc[mf][nf], 0, 0, 0);
      }
  };

  stageB(0, 0);
  loadA(0);
  writeA(0);
  __syncthreads();
  for (int t = 0; t < nt; ++t) {
    int cur = t & 1, nxt = cur ^ 1;
    if (t + 1 < nt) {
      stageB(t + 1, nxt);
      loadA(t + 1);  // regs now; vmcnt wait lands in writeA (after compute)
    }
    compute(cur);
    if (t + 1 < nt) writeA(nxt);
    __syncthreads();
  }

  // epilogue: descale and write partial conv tiles
  const float sx = 1.f / 4096.f;
  const float sc = 1.f / (4096.f * 4096.f);
  float* base = convbuf + ((long)ks * NN + n0) * 1024;
#pragma unroll
  for (int mf = 0; mf < 4; ++mf) {
#pragma unroll
    for (int nf = 0; nf < 4; ++nf) {
      int o = wc * 64 + nf * 16 + fr;
#pragma unroll
      for (int j = 0; j < 4; ++j) {
        int n = wr * 64 + mf * 16 + fg * 4 + j;
        base[(long)n * 1024 + kc * 128 + o] = accx[mf][nf][j] * sx;
        base[(long)n * 1024 + 512 + kc * 128 + o] = accc[mf][nf][j] * sc;
      }
    }
  }
}

// ---------------------------------------------------------------- K3: epilogue
__global__ __launch_bounds__(256) void k3_out(
    const float* __restrict__ convbuf, const float* __restrict__ gamma,
    float* __restrict__ out, int nks) {
  int gid = blockIdx.x * 256 + threadIdx.x;  // over 4096*128
  int n = gid >> 7, o = gid & 127;
  float cx[KK], cc[KK];
#pragma unroll
  for (int k = 0; k < KK; ++k) {
    cx[k] = 0.f;
    cc[k] = 0.f;
  }
  for (int s = 0; s < nks; ++s) {
    const float* bp = convbuf + ((long)s * NN + n) * 1024;
#pragma unroll
    for (int k = 0; k < KK; ++k) {
      cx[k] += bp[k * 128 + o];
      cc[k] += bp[512 + k * 128 + o];
    }
  }
  const float inv_sqrt_2pi = 0.3989422804014327f;
  float r = 0.f;
#pragma unroll
  for (int k = 0; k < KK; ++k) {
    float s = cc[k];
    bool iz = (s == 0.f);
    float ss = iz ? 1e-10f : s;
    float sq = sqrtf(ss);
    float w = cx[k] / sq;
    float nr = sq * (expf(-0.5f * w * w) * inv_sqrt_2pi +
                     0.5f * w * (1.f + erff(w * 0.7071067811865476f)));
    float ex = iz ? fmaxf(cx[k], 0.f) : nr;
    r += ex * gamma[k * NN + n];
  }
  out[gid] = r;
}

extern "C" void kernel_launch(void* const* d_in, const int* in_sizes, int n_in,
                              void* d_out, int out_size, void* d_ws, size_t ws_size,
                              hipStream_t stream) {
  const float* shift = (const float*)d_in[0];
  const float* feats = (const float*)d_in[1];
  const float* W = (const float*)d_in[2];
  const float* pi = (const float*)d_in[3];
  const float* mu = (const float*)d_in[4];
  const float* sigma = (const float*)d_in[5];
  // d_in[6] = A2 is unused: recomputed in-register as shift^2 (saves 64 MB reads)
  float* out = (float*)d_out;

  char* w = (char*)d_ws;
  f16* Wx = (f16*)w;        w += 16384 * 2;
  f16* Wc = (f16*)w;        w += 16384 * 2;
  f16* muh = (f16*)w;       w += 512 * 2;
  f16* varh = (f16*)w;      w += 512 * 2;
  float* invvar = (float*)w; w += 512 * 4;
  float* gamma = (float*)w; w += (size_t)KK * NN * 4;
  f16* Bws = (f16*)w;       w += (size_t)1024 * NN * 2;
  float* convbuf = (float*)w;
  size_t used = (size_t)(w - (char*)d_ws);
  size_t slab = (size_t)NN * 1024 * 4;  // 16 MB per k-split slice
  int nks = 1;
  if (ws_size >= used + 4 * slab) nks = 4;
  else if (ws_size >= used + 2 * slab) nks = 2;

  hipLaunchKernelGGL(k0_prep, dim3(64), dim3(256), 0, stream, W, mu, sigma, Wx, Wc,
                     muh, varh, invvar);
  hipLaunchKernelGGL(k1a_gamma, dim3(NN / 4), dim3(256), 0, stream, feats, mu, pi,
                     invvar, gamma);
  hipLaunchKernelGGL(k1b_transform, dim3(4 * 32), dim3(256), 0, stream, feats, Wx, Wc,
                     muh, varh, Bws);
  hipLaunchKernelGGL(k2_conv, dim3(nks * 4 * 32), dim3(256), 0, stream, shift, Bws,
                     convbuf, NN / nks);
  hipLaunchKernelGGL(k3_out, dim3(NN * 128 / 256), dim3(256), 0, stream, convbuf,
                     gamma, out, nks);
}